// Round 1
// 361.849 us; speedup vs baseline: 1.0066x; 1.0066x over previous
//
#include <hip/hip_runtime.h>
#include <math.h>

#define EPS_F 1e-6f
#define RPW 4   // rows per wave (software-pipelined)

// Persistent waves: 2048 blocks x 4 waves, each wave owns RPW=4 rows strided
// by the total wave count (keeps cross-wave coalescing identical each step).
// Row j+1's loads (8 x float4 = 8 KiB/wave) + tgt prefetch are issued BEFORE
// row j's reduction chains, so the serial shfl/exp/scalar-epilogue latency of
// one row hides under the next row's memory traffic.
__global__ __launch_bounds__(256) void focal_row_kernel(
    const float* __restrict__ x, const int* __restrict__ tgt,
    const float* __restrict__ cw, float* __restrict__ partial,
    int B, int C)
{
    const int wave = threadIdx.x >> 6;
    const int lane = threadIdx.x & 63;
    const int wid  = blockIdx.x * 4 + wave;   // global wave id
    const int nw   = gridDim.x * 4;           // total waves

    float acc = 0.0f;

    int row = wid;
    float4 f[8];
    int t = 0;
    if (row < B) {
        const float4* xr = (const float4*)(x + (size_t)row * (size_t)C);
#pragma unroll
        for (int i = 0; i < 8; ++i) f[i] = xr[lane + 64 * i];
        t = tgt[row];                          // wave-uniform broadcast load
    }

#pragma unroll
    for (int j = 0; j < RPW; ++j) {
        const int nrow = row + nw;
        float4 g[8];
        int tn = 0;
        // issue next row's loads before touching this row's data
        if (j + 1 < RPW && nrow < B) {
            const float4* xn = (const float4*)(x + (size_t)nrow * (size_t)C);
#pragma unroll
            for (int i = 0; i < 8; ++i) g[i] = xn[lane + 64 * i];
            tn = tgt[nrow];
        }

        if (row < B) {
            // wave-uniform broadcast loads (1 transaction each); issued early
            // so their latency hides under the shuffle-reduce chains below.
            const float xt = x[(size_t)row * (size_t)C + (size_t)t];
            const float xd = x[(size_t)row * (size_t)C + (size_t)(C - 1)];
            const float w  = cw[t];

            float m = -3.4e38f;
#pragma unroll
            for (int i = 0; i < 8; ++i)
                m = fmaxf(m, fmaxf(fmaxf(f[i].x, f[i].y), fmaxf(f[i].z, f[i].w)));
#pragma unroll
            for (int off = 32; off > 0; off >>= 1)
                m = fmaxf(m, __shfl_xor(m, off, 64));

            // 4 independent accumulators: breaks the 32-long dependent add chain
            float s0 = 0.0f, s1 = 0.0f, s2 = 0.0f, s3 = 0.0f;
#pragma unroll
            for (int i = 0; i < 8; ++i) {
                s0 += __expf(f[i].x - m);
                s1 += __expf(f[i].y - m);
                s2 += __expf(f[i].z - m);
                s3 += __expf(f[i].w - m);
            }
            float s = (s0 + s1) + (s2 + s3);
#pragma unroll
            for (int off = 32; off > 0; off >>= 1)
                s += __shfl_xor(s, off, 64);

            const float inv_s = 1.0f / s;
            const float pt = __expf(xt - m) * inv_s;
            const float pd = __expf(xd - m) * inv_s;
            const float log_pt   = __logf(pt == 0.0f ? pt + EPS_F : pt);
            const float pt2      = (pt == 1.0f) ? (1.0f - EPS_F) * pt : pt;
            const float log_1mpt = __logf(1.0f - pt2);
            // all lanes compute the same value; only lane 0's is consumed
            acc += w * (-log_pt * (1.0f - pd) - log_1mpt * pd);
        }

        if (j + 1 < RPW) {
#pragma unroll
            for (int i = 0; i < 8; ++i) f[i] = g[i];
            t = tn;
        }
        row = nrow;
    }

    __shared__ float sm[4];
    if (lane == 0) sm[wave] = acc;
    __syncthreads();
    if (threadIdx.x == 0)
        partial[blockIdx.x] = sm[0] + sm[1] + sm[2] + sm[3];
}

// Single-block deterministic reduction of block partials.
__global__ __launch_bounds__(256) void reduce_partials_kernel(
    const float* __restrict__ p, float* __restrict__ out, int n, float invB)
{
    float s = 0.0f;
    for (int i = threadIdx.x; i < n; i += 256) s += p[i];
#pragma unroll
    for (int off = 32; off > 0; off >>= 1)
        s += __shfl_xor(s, off, 64);
    __shared__ float sm[4];
    const int wave = threadIdx.x >> 6;
    const int lane = threadIdx.x & 63;
    if (lane == 0) sm[wave] = s;
    __syncthreads();
    if (threadIdx.x == 0)
        out[0] = (sm[0] + sm[1] + sm[2] + sm[3]) * invB;
}

extern "C" void kernel_launch(void* const* d_in, const int* in_sizes, int n_in,
                              void* d_out, int out_size, void* d_ws, size_t ws_size,
                              hipStream_t stream)
{
    const float* x   = (const float*)d_in[0];   // (B, C) fp32 logits
    const int*   tgt = (const int*)d_in[1];     // (B,) int32 targets
    const float* cw  = (const float*)d_in[2];   // (C,) fp32 class weights

    const int B = in_sizes[1];                  // 32768
    const int C = in_sizes[2];                  // 2048
    float* out = (float*)d_out;
    float* partial = (float*)d_ws;

    const int nblocks = (B + 4 * RPW - 1) / (4 * RPW);   // 2048 for B=32768
    focal_row_kernel<<<nblocks, 256, 0, stream>>>(x, tgt, cw, partial, B, C);
    reduce_partials_kernel<<<1, 256, 0, stream>>>(partial, out, nblocks,
                                                  1.0f / (float)B);
}